// Round 2
// baseline (519.818 us; speedup 1.0000x reference)
//
#include <hip/hip_runtime.h>

#define T_   2048
#define BB   2
#define CC   2048
#define HH   16
#define GG   4
#define HSS  128
#define QKVD 3072          // (H+2G)*HS
#define NQKV 3088          // + H gate cols
#define NPAD 3200          // padded to 25*128
#define SCALE_ 0.08838834764831845f   // 1/sqrt(128)

typedef __attribute__((ext_vector_type(8))) short  short8;
typedef __attribute__((ext_vector_type(4))) float  f32x4;
typedef __attribute__((ext_vector_type(4))) int    v4i;
typedef __attribute__((ext_vector_type(4))) float  v4f;
typedef __attribute__((ext_vector_type(4))) unsigned short u16x4;

__device__ __forceinline__ unsigned short f2bf(float f) {
    unsigned u = __float_as_uint(f);
    u += 0x7fffu + ((u >> 16) & 1u);   // RNE
    return (unsigned short)(u >> 16);
}
__device__ __forceinline__ float bf2f(unsigned short h) {
    return __uint_as_float(((unsigned)h) << 16);
}

// ---------------- f32 -> bf16 convert (with optional zero-pad tail) ----------------
__global__ void k_convert(const float* __restrict__ src, unsigned short* __restrict__ dst,
                          int n_src4, int n_dst4) {
    int i = blockIdx.x * blockDim.x + threadIdx.x;
    if (i >= n_dst4) return;
    u16x4 o;
    if (i < n_src4) {
        v4f v = *(const v4f*)(src + (size_t)i * 4);
        o[0] = f2bf(v[0]); o[1] = f2bf(v[1]); o[2] = f2bf(v[2]); o[3] = f2bf(v[3]);
    } else {
        o[0] = 0; o[1] = 0; o[2] = 0; o[3] = 0;
    }
    *(u16x4*)(dst + (size_t)i * 4) = o;
}

// ---------------- NT GEMM: C[m][n] = sum_k A[m][k]*B[n][k], bf16 in ----------------
// OutT = unsigned short (bf16 store) or float (f32 store)
template <typename OutT>
__launch_bounds__(256, 2)
__global__ void k_gemm_nt(const unsigned short* __restrict__ A,
                          const unsigned short* __restrict__ Bm,
                          OutT* __restrict__ C,
                          int K, int lda, int ldb, int ldc) {
    __shared__ unsigned short As[128 * 64];
    __shared__ unsigned short Bs[128 * 64];
    const int t    = threadIdx.x;
    const int lane = t & 63;
    const int wid  = t >> 6;
    const int bm = blockIdx.x, bn = blockIdx.y;
    const int wm = (wid >> 1) * 64, wn = (wid & 1) * 64;
    const int srow = t >> 3;          // 0..31
    const int scol = (t & 7) * 8;     // 0..56
    const unsigned short* Ag = A  + (size_t)(bm * 128 + srow) * lda + scol;
    const unsigned short* Bg = Bm + (size_t)(bn * 128 + srow) * ldb + scol;

    f32x4 acc[4][4];
#pragma unroll
    for (int i = 0; i < 4; ++i)
#pragma unroll
        for (int j = 0; j < 4; ++j)
            acc[i][j] = (f32x4){0.f, 0.f, 0.f, 0.f};

    const int fro = lane & 15;
    const int fko = (lane >> 4) * 8;

    for (int kt = 0; kt < K; kt += 64) {
        __syncthreads();
#pragma unroll
        for (int r = 0; r < 4; ++r) {
            *(v4i*)&As[(srow + r * 32) * 64 + scol] = *(const v4i*)(Ag + (size_t)(r * 32) * lda + kt);
            *(v4i*)&Bs[(srow + r * 32) * 64 + scol] = *(const v4i*)(Bg + (size_t)(r * 32) * ldb + kt);
        }
        __syncthreads();
#pragma unroll
        for (int kk = 0; kk < 2; ++kk) {
            short8 af[4], bfr[4];
#pragma unroll
            for (int i = 0; i < 4; ++i)
                af[i] = *(const short8*)&As[(wm + i * 16 + fro) * 64 + kk * 32 + fko];
#pragma unroll
            for (int j = 0; j < 4; ++j)
                bfr[j] = *(const short8*)&Bs[(wn + j * 16 + fro) * 64 + kk * 32 + fko];
#pragma unroll
            for (int i = 0; i < 4; ++i)
#pragma unroll
                for (int j = 0; j < 4; ++j)
                    acc[i][j] = __builtin_amdgcn_mfma_f32_16x16x32_bf16(af[i], bfr[j], acc[i][j], 0, 0, 0);
        }
    }
    const int col = lane & 15, rbase = (lane >> 4) * 4;
#pragma unroll
    for (int i = 0; i < 4; ++i)
#pragma unroll
        for (int j = 0; j < 4; ++j)
#pragma unroll
            for (int r = 0; r < 4; ++r) {
                int grow = bm * 128 + wm + i * 16 + rbase + r;
                int gcol = bn * 128 + wn + j * 16 + col;
                float v = acc[i][j][r];
                if constexpr (sizeof(OutT) == 2)
                    C[(size_t)grow * ldc + gcol] = (OutT)f2bf(v);
                else
                    C[(size_t)grow * ldc + gcol] = (OutT)v;
            }
}

// ---------------- fused RMSNorm + RoPE, in place on q/k regions of qkv -------------
__global__ void k_normrope(unsigned short* __restrict__ qkv,
                           const float* __restrict__ cosT, const float* __restrict__ sinT,
                           const float* __restrict__ qw, const float* __restrict__ kw) {
    const int lane = threadIdx.x & 63;
    const int row  = blockIdx.x * 4 + (threadIdx.x >> 6);  // 0 .. 4096*20-1
    const int tok  = row / 20;
    const int hh   = row - tok * 20;
    const int tpos = tok & (T_ - 1);
    unsigned short* rp = qkv + (size_t)tok * NPAD + (hh < 16 ? hh * 128 : 2048 + (hh - 16) * 128);
    const float* w = (hh < 16) ? qw : kw;
    float e1 = bf2f(rp[lane]);
    float e2 = bf2f(rp[lane + 64]);
    float ss = e1 * e1 + e2 * e2;
#pragma unroll
    for (int m = 1; m < 64; m <<= 1) ss += __shfl_xor(ss, m);
    float inv = rsqrtf(ss * (1.0f / 128.0f) + 1e-5f);
    float n1 = e1 * inv * w[lane];
    float n2 = e2 * inv * w[lane + 64];
    float c = cosT[tpos * 64 + lane];
    float s = sinT[tpos * 64 + lane];
    rp[lane]      = f2bf(n1 * c - n2 * s);
    rp[lane + 64] = f2bf(n2 * c + n1 * s);
}

// ---------------- V transpose: VT[b][g][d][s] = V[b][s][g][d] ----------------------
__global__ void k_transposeV(const unsigned short* __restrict__ qkv,
                             unsigned short* __restrict__ vt) {
    __shared__ unsigned short tile[64][65];
    const int b = blockIdx.x >> 2, g = blockIdx.x & 3;
    const int s0 = blockIdx.y * 64, d0 = blockIdx.z * 64;
    const int tx = threadIdx.x & 63, ty0 = threadIdx.x >> 6;
    const unsigned short* src = qkv + (size_t)(b * T_ + s0) * NPAD + 2560 + g * 128 + d0;
#pragma unroll
    for (int r = 0; r < 16; ++r) {
        int ty = ty0 * 16 + r;
        tile[ty][tx] = src[(size_t)ty * NPAD + tx];
    }
    __syncthreads();
    unsigned short* dstp = vt + ((size_t)(b * GG + g) * 128 + d0) * T_ + s0;
#pragma unroll
    for (int r = 0; r < 16; ++r) {
        int ty = ty0 * 16 + r;
        dstp[(size_t)ty * T_ + tx] = tile[tx][ty];
    }
}

// ---------------- flash attention + gate ------------------------------------------
__launch_bounds__(256, 2)
__global__ void k_attn(const unsigned short* __restrict__ qkv,
                       const unsigned short* __restrict__ vt,
                       unsigned short* __restrict__ ao) {
    __shared__ unsigned short Plds[4][16 * 32];
    const int lane = threadIdx.x & 63;
    const int wid  = threadIdx.x >> 6;
    const int bh = blockIdx.x;
    const int b = bh >> 4, h = bh & 15, g = h >> 2;
    const int qt = (int)gridDim.y - 1 - (int)blockIdx.y;   // long blocks first
    const int q0 = qt * 64 + wid * 16;
    const int fro = lane & 15, fk = lane >> 4;
    const int rbase = fk * 4;

    // Q fragments (A-operand): row q0+fro, k = kb*32 + fk*8 .. +8
    const unsigned short* qp = qkv + (size_t)(b * T_ + q0 + fro) * NPAD + h * 128 + fk * 8;
    short8 qf[4];
#pragma unroll
    for (int kb = 0; kb < 4; ++kb) qf[kb] = *(const short8*)(qp + kb * 32);

    const unsigned short* kbp = qkv + (size_t)(b * T_) * NPAD + 2048 + g * 128 + fk * 8;
    const unsigned short* vbp = vt + ((size_t)(b * GG + g) * 128) * T_;

    float m_r[4], l_r[4];
    f32x4 o[8];
#pragma unroll
    for (int r = 0; r < 4; ++r) { m_r[r] = -1e30f; l_r[r] = 0.f; }
#pragma unroll
    for (int d = 0; d < 8; ++d) o[d] = (f32x4){0.f, 0.f, 0.f, 0.f};

    const int nt = ((q0 + 15) >> 5) + 1;
    for (int ti = 0; ti < nt; ++ti) {
        const int s0 = ti * 32;
        f32x4 sc[2];
        sc[0] = (f32x4){0.f, 0.f, 0.f, 0.f};
        sc[1] = (f32x4){0.f, 0.f, 0.f, 0.f};
#pragma unroll
        for (int jb = 0; jb < 2; ++jb)
#pragma unroll
            for (int kb = 0; kb < 4; ++kb) {
                short8 kf = *(const short8*)(kbp + (size_t)(s0 + jb * 16 + fro) * NPAD + kb * 32);
                sc[jb] = __builtin_amdgcn_mfma_f32_16x16x32_bf16(qf[kb], kf, sc[jb], 0, 0, 0);
            }
        // scale + causal mask
        float pv[2][4];
        const bool domask = (s0 + 31 > q0);
#pragma unroll
        for (int jb = 0; jb < 2; ++jb)
#pragma unroll
            for (int r = 0; r < 4; ++r) {
                float v = sc[jb][r] * SCALE_;
                if (domask) {
                    int qg = q0 + rbase + r;
                    int kg = s0 + jb * 16 + fro;
                    if (kg > qg) v = -1e30f;
                }
                pv[jb][r] = v;
            }
        // row max over the 16-lane group
        float mx[4];
#pragma unroll
        for (int r = 0; r < 4; ++r) mx[r] = fmaxf(pv[0][r], pv[1][r]);
#pragma unroll
        for (int msk = 1; msk < 16; msk <<= 1)
#pragma unroll
            for (int r = 0; r < 4; ++r) mx[r] = fmaxf(mx[r], __shfl_xor(mx[r], msk));
        float fs[4];
#pragma unroll
        for (int r = 0; r < 4; ++r) {
            float mn = fmaxf(m_r[r], mx[r]);
            fs[r] = __expf(m_r[r] - mn);
            m_r[r] = mn;
        }
#pragma unroll
        for (int jb = 0; jb < 2; ++jb)
#pragma unroll
            for (int r = 0; r < 4; ++r) pv[jb][r] = __expf(pv[jb][r] - m_r[r]);
        float rs[4];
#pragma unroll
        for (int r = 0; r < 4; ++r) rs[r] = pv[0][r] + pv[1][r];
#pragma unroll
        for (int msk = 1; msk < 16; msk <<= 1)
#pragma unroll
            for (int r = 0; r < 4; ++r) rs[r] += __shfl_xor(rs[r], msk);
#pragma unroll
        for (int r = 0; r < 4; ++r) l_r[r] = l_r[r] * fs[r] + rs[r];
#pragma unroll
        for (int d = 0; d < 8; ++d)
#pragma unroll
            for (int r = 0; r < 4; ++r) o[d][r] *= fs[r];
        // P -> LDS (transpose to A-operand layout), bf16
        unsigned short* pl = &Plds[wid][0];
#pragma unroll
        for (int jb = 0; jb < 2; ++jb)
#pragma unroll
            for (int r = 0; r < 4; ++r)
                pl[(rbase + r) * 32 + jb * 16 + fro] = f2bf(pv[jb][r]);
        asm volatile("s_waitcnt lgkmcnt(0)" ::: "memory");
        short8 pa = *(const short8*)&Plds[wid][fro * 32 + fk * 8];
        // PV
#pragma unroll
        for (int db = 0; db < 8; ++db) {
            short8 vf = *(const short8*)(vbp + (size_t)(db * 16 + fro) * T_ + s0 + fk * 8);
            o[db] = __builtin_amdgcn_mfma_f32_16x16x32_bf16(pa, vf, o[db], 0, 0, 0);
        }
    }
    // epilogue: 1/l, sigmoid gate, store bf16
#pragma unroll
    for (int r = 0; r < 4; ++r) {
        int qrow = q0 + rbase + r;
        float gv = bf2f(qkv[(size_t)(b * T_ + qrow) * NPAD + QKVD + h]);
        float sg = 1.f / (1.f + __expf(-gv));
        float invl = sg / l_r[r];
        unsigned short* orow = ao + (size_t)(b * T_ + qrow) * 2048 + h * 128;
#pragma unroll
        for (int db = 0; db < 8; ++db)
            orow[db * 16 + fro] = f2bf(o[db][r] * invl);
    }
}

extern "C" void kernel_launch(void* const* d_in, const int* in_sizes, int n_in,
                              void* d_out, int out_size, void* d_ws, size_t ws_size,
                              hipStream_t stream) {
    const float* x      = (const float*)d_in[0];
    const float* cosT   = (const float*)d_in[1];
    const float* sinT   = (const float*)d_in[2];
    const float* W_attn = (const float*)d_in[3];
    const float* qw     = (const float*)d_in[4];
    const float* kw     = (const float*)d_in[5];
    const float* W_proj = (const float*)d_in[6];

    char* ws = (char*)d_ws;
    const size_t OFF_XB   = 0;                       // 4096*2048*2   = 16777216
    const size_t OFF_WAB  = 16777216;                // 3200*2048*2   = 13107200
    const size_t OFF_WPB  = 29884416;                // 2048*2048*2   =  8388608
    const size_t OFF_QKV  = 38273024;                // 4096*3200*2   = 26214400
    const size_t OFF_VT   = 64487424;                // 2*4*128*2048*2=  4194304
    const size_t OFF_AO   = 68681728;                // 4096*2048*2   = 16777216
    const size_t NEED     = 85458944;
    if (ws_size < NEED) return;   // workspace too small: fail loudly (zeros out)

    unsigned short* xb   = (unsigned short*)(ws + OFF_XB);
    unsigned short* wab  = (unsigned short*)(ws + OFF_WAB);
    unsigned short* wpb  = (unsigned short*)(ws + OFF_WPB);
    unsigned short* qkvb = (unsigned short*)(ws + OFF_QKV);
    unsigned short* vtb  = (unsigned short*)(ws + OFF_VT);
    unsigned short* aob  = (unsigned short*)(ws + OFF_AO);

    // converts
    k_convert<<<8192, 256, 0, stream>>>(x,      xb,  2097152, 2097152);
    k_convert<<<6400, 256, 0, stream>>>(W_attn, wab, 1581056, 1638400);  // pad rows 3088..3199 = 0
    k_convert<<<4096, 256, 0, stream>>>(W_proj, wpb, 1048576, 1048576);
    // qkv GEMM: (4096 x 3200) = xb (4096x2048) * wab^T  -> bf16
    k_gemm_nt<unsigned short><<<dim3(32, 25), 256, 0, stream>>>(xb, wab, qkvb, 2048, 2048, 2048, NPAD);
    // rmsnorm + rope in place
    k_normrope<<<20480, 256, 0, stream>>>(qkvb, cosT, sinT, qw, kw);
    // V transpose
    k_transposeV<<<dim3(8, 32, 2), 256, 0, stream>>>(qkvb, vtb);
    // attention + gate
    k_attn<<<dim3(32, 32), 256, 0, stream>>>(qkvb, vtb, aob);
    // output projection -> f32 d_out (reference output dtype is float32!)
    k_gemm_nt<float><<<dim3(32, 16), 256, 0, stream>>>(aob, wpb, (float*)d_out, 2048, 2048, 2048, 2048);
}

// Round 3
// 339.189 us; speedup vs baseline: 1.5325x; 1.5325x over previous
//
#include <hip/hip_runtime.h>

#define T_   2048
#define BB   2
#define CC   2048
#define HH   16
#define GG   4
#define HSS  128
#define QKVD 3072          // (H+2G)*HS
#define NQKV 3088          // + H gate cols
#define NPAD 3200          // padded to 25*128
#define SCALE_ 0.08838834764831845f   // 1/sqrt(128)

typedef __attribute__((ext_vector_type(8))) short  short8;
typedef __attribute__((ext_vector_type(4))) float  f32x4;
typedef __attribute__((ext_vector_type(4))) int    v4i;
typedef __attribute__((ext_vector_type(4))) float  v4f;
typedef __attribute__((ext_vector_type(4))) unsigned short u16x4;

typedef const void __attribute__((address_space(1)))* gas1_t;
typedef void __attribute__((address_space(3)))* as3_t;

__device__ __forceinline__ void gl_lds16(const void* g, void* l) {
    __builtin_amdgcn_global_load_lds((gas1_t)g, (as3_t)l, 16, 0, 0);
}

__device__ __forceinline__ unsigned short f2bf(float f) {
    unsigned u = __float_as_uint(f);
    u += 0x7fffu + ((u >> 16) & 1u);   // RNE
    return (unsigned short)(u >> 16);
}
__device__ __forceinline__ float bf2f(unsigned short h) {
    return __uint_as_float(((unsigned)h) << 16);
}

// ---------------- f32 -> bf16 convert (with optional zero-pad tail) ----------------
__global__ void k_convert(const float* __restrict__ src, unsigned short* __restrict__ dst,
                          int n_src4, int n_dst4) {
    int i = blockIdx.x * blockDim.x + threadIdx.x;
    if (i >= n_dst4) return;
    u16x4 o;
    if (i < n_src4) {
        v4f v = *(const v4f*)(src + (size_t)i * 4);
        o[0] = f2bf(v[0]); o[1] = f2bf(v[1]); o[2] = f2bf(v[2]); o[3] = f2bf(v[3]);
    } else {
        o[0] = 0; o[1] = 0; o[2] = 0; o[3] = 0;
    }
    *(u16x4*)(dst + (size_t)i * 4) = o;
}

// ---------------- NT GEMM: C[m][n] = sum_k A[m][k]*B[n][k], bf16 in ----------------
// m97 structure: global_load_lds width-16 staging, linear LDS, 2-barrier loop.
template <typename OutT>
__launch_bounds__(256, 2)
__global__ void k_gemm_nt(const unsigned short* __restrict__ A,
                          const unsigned short* __restrict__ Bm,
                          OutT* __restrict__ C,
                          int K, int lda, int ldb, int ldc) {
    __shared__ unsigned short As[128 * 64];
    __shared__ unsigned short Bs[128 * 64];
    const int t    = threadIdx.x;
    const int lane = t & 63;
    const int wid  = t >> 6;
    const int bm = blockIdx.x, bn = blockIdx.y;
    const int wm = (wid >> 1) * 64, wn = (wid & 1) * 64;

    f32x4 acc[4][4];
#pragma unroll
    for (int i = 0; i < 4; ++i)
#pragma unroll
        for (int j = 0; j < 4; ++j)
            acc[i][j] = (f32x4){0.f, 0.f, 0.f, 0.f};

    const int fro = lane & 15;
    const int fko = (lane >> 4) * 8;
    // staging: wave stages rows wid*32 + p*8 .. +8 ; lane -> row +(l>>3), chunk (l&7)*8
    const int lrow = lane >> 3, lcol = (lane & 7) * 8;

    for (int kt = 0; kt < K; kt += 64) {
        __syncthreads();
#pragma unroll
        for (int p = 0; p < 4; ++p) {
            const int ra = wid * 32 + p * 8;
            gl_lds16(A  + (size_t)(bm * 128 + ra + lrow) * lda + kt + lcol, &As[ra * 64]);
            gl_lds16(Bm + (size_t)(bn * 128 + ra + lrow) * ldb + kt + lcol, &Bs[ra * 64]);
        }
        __syncthreads();
#pragma unroll
        for (int kk = 0; kk < 2; ++kk) {
            short8 af[4], bfr[4];
#pragma unroll
            for (int i = 0; i < 4; ++i)
                af[i] = *(const short8*)&As[(wm + i * 16 + fro) * 64 + kk * 32 + fko];
#pragma unroll
            for (int j = 0; j < 4; ++j)
                bfr[j] = *(const short8*)&Bs[(wn + j * 16 + fro) * 64 + kk * 32 + fko];
#pragma unroll
            for (int i = 0; i < 4; ++i)
#pragma unroll
                for (int j = 0; j < 4; ++j)
                    acc[i][j] = __builtin_amdgcn_mfma_f32_16x16x32_bf16(af[i], bfr[j], acc[i][j], 0, 0, 0);
        }
    }
    const int col = lane & 15, rbase = (lane >> 4) * 4;
#pragma unroll
    for (int i = 0; i < 4; ++i)
#pragma unroll
        for (int j = 0; j < 4; ++j)
#pragma unroll
            for (int r = 0; r < 4; ++r) {
                int grow = bm * 128 + wm + i * 16 + rbase + r;
                int gcol = bn * 128 + wn + j * 16 + col;
                float v = acc[i][j][r];
                if constexpr (sizeof(OutT) == 2)
                    C[(size_t)grow * ldc + gcol] = (OutT)f2bf(v);
                else
                    C[(size_t)grow * ldc + gcol] = (OutT)v;
            }
}

// ---------------- fused RMSNorm + RoPE, in place on q/k regions of qkv -------------
__global__ void k_normrope(unsigned short* __restrict__ qkv,
                           const float* __restrict__ cosT, const float* __restrict__ sinT,
                           const float* __restrict__ qw, const float* __restrict__ kw) {
    const int lane = threadIdx.x & 63;
    const int row  = blockIdx.x * 4 + (threadIdx.x >> 6);  // 0 .. 4096*20-1
    const int tok  = row / 20;
    const int hh   = row - tok * 20;
    const int tpos = tok & (T_ - 1);
    unsigned short* rp = qkv + (size_t)tok * NPAD + (hh < 16 ? hh * 128 : 2048 + (hh - 16) * 128);
    const float* w = (hh < 16) ? qw : kw;
    float e1 = bf2f(rp[lane]);
    float e2 = bf2f(rp[lane + 64]);
    float ss = e1 * e1 + e2 * e2;
#pragma unroll
    for (int m = 1; m < 64; m <<= 1) ss += __shfl_xor(ss, m);
    float inv = rsqrtf(ss * (1.0f / 128.0f) + 1e-5f);
    float n1 = e1 * inv * w[lane];
    float n2 = e2 * inv * w[lane + 64];
    float c = cosT[tpos * 64 + lane];
    float s = sinT[tpos * 64 + lane];
    rp[lane]      = f2bf(n1 * c - n2 * s);
    rp[lane + 64] = f2bf(n2 * c + n1 * s);
}

// ---------------- V transpose: VT[b][g][d][s] = V[b][s][g][d] ----------------------
__global__ void k_transposeV(const unsigned short* __restrict__ qkv,
                             unsigned short* __restrict__ vt) {
    __shared__ unsigned short tile[64][65];
    const int b = blockIdx.x >> 2, g = blockIdx.x & 3;
    const int s0 = blockIdx.y * 64, d0 = blockIdx.z * 64;
    const int tx = threadIdx.x & 63, ty0 = threadIdx.x >> 6;
    const unsigned short* src = qkv + (size_t)(b * T_ + s0) * NPAD + 2560 + g * 128 + d0;
#pragma unroll
    for (int r = 0; r < 16; ++r) {
        int ty = ty0 * 16 + r;
        tile[ty][tx] = src[(size_t)ty * NPAD + tx];
    }
    __syncthreads();
    unsigned short* dstp = vt + ((size_t)(b * GG + g) * 128 + d0) * T_ + s0;
#pragma unroll
    for (int r = 0; r < 16; ++r) {
        int ty = ty0 * 16 + r;
        dstp[(size_t)ty * T_ + tx] = tile[tx][ty];
    }
}

// ---------------- flash attention + gate ------------------------------------------
// 4 waves x 32 q-rows = 128 q/block; KVBLK=64; K/V staged in swizzled LDS shared
// by all waves; per-wave P in padded LDS (stride 72 u16).
__launch_bounds__(256, 2)
__global__ void k_attn(const unsigned short* __restrict__ qkv,
                       const unsigned short* __restrict__ vt,
                       unsigned short* __restrict__ ao) {
    __shared__ unsigned short Ks[64 * 128];   // rows kv, swizzled 16B slots
    __shared__ unsigned short Vs[128 * 64];   // rows d,  swizzled 16B slots
    __shared__ unsigned short Ps[4][32 * 72];
    const int t = threadIdx.x;
    const int lane = t & 63;
    const int wid  = t >> 6;
    const int id = blockIdx.x;
    const int bh = (id & 7) * 4 + ((id >> 3) & 3);   // 4 bh per XCD, same g-group
    const int qt = 15 - (id >> 5);                   // long blocks dispatched first
    const int b = bh >> 4, h = bh & 15, g = h >> 2;
    const int fro = lane & 15, fk = lane >> 4;
    const int rbase = fk * 4;
    const int q0w = qt * 128 + wid * 32;

    // Q fragments: rows q0w + i*16 + fro, k = kb*32 + fk*8
    short8 qf[2][4];
#pragma unroll
    for (int i = 0; i < 2; ++i) {
        const unsigned short* qp = qkv + (size_t)(b * T_ + q0w + i * 16 + fro) * NPAD + h * 128 + fk * 8;
#pragma unroll
        for (int kb = 0; kb < 4; ++kb) qf[i][kb] = *(const short8*)(qp + kb * 32);
    }

    const unsigned short* kg0 = qkv + (size_t)(b * T_) * NPAD + 2048 + g * 128;
    const unsigned short* vg0 = vt + (size_t)(b * GG + g) * 128 * T_;

    float m_r[2][4], l_r[2][4];
    f32x4 o[2][8];
#pragma unroll
    for (int i = 0; i < 2; ++i)
#pragma unroll
        for (int r = 0; r < 4; ++r) { m_r[i][r] = -1e30f; l_r[i][r] = 0.f; }
#pragma unroll
    for (int i = 0; i < 2; ++i)
#pragma unroll
        for (int d = 0; d < 8; ++d) o[i][d] = (f32x4){0.f, 0.f, 0.f, 0.f};

    const int nt = qt * 2 + 2;
    const int tmax_w = (q0w + 31) >> 6;
    for (int ti = 0; ti < nt; ++ti) {
        const int s0 = ti * 64;
        __syncthreads();
        // stage K tile [64][128]
#pragma unroll
        for (int p = 0; p < 4; ++p) {
            const int kr = p * 16 + (t >> 4);
            const int c  = t & 15;
            v4i tmp = *(const v4i*)(kg0 + (size_t)(s0 + kr) * NPAD + c * 8);
            *(v4i*)&Ks[kr * 128 + 8 * (c ^ (kr & 7))] = tmp;
        }
        // stage V^T tile [128][64]
#pragma unroll
        for (int p = 0; p < 4; ++p) {
            const int d  = p * 32 + (t >> 3);
            const int sv = t & 7;
            v4i tmp = *(const v4i*)(vg0 + (size_t)d * T_ + s0 + sv * 8);
            *(v4i*)&Vs[d * 64 + 8 * (sv ^ (d & 7))] = tmp;
        }
        __syncthreads();
        if (ti > tmax_w) continue;   // wave-uniform skip; barriers still balanced

        // ---- QK^T: S[q 32][kv 64] ----
        f32x4 sc[2][4];
#pragma unroll
        for (int i = 0; i < 2; ++i)
#pragma unroll
            for (int jb = 0; jb < 4; ++jb) sc[i][jb] = (f32x4){0.f, 0.f, 0.f, 0.f};
#pragma unroll
        for (int jb = 0; jb < 4; ++jb) {
            const int kr = jb * 16 + fro;
#pragma unroll
            for (int kb = 0; kb < 4; ++kb) {
                short8 kf = *(const short8*)&Ks[kr * 128 + 8 * ((kb * 4 + fk) ^ (kr & 7))];
#pragma unroll
                for (int i = 0; i < 2; ++i)
                    sc[i][jb] = __builtin_amdgcn_mfma_f32_16x16x32_bf16(qf[i][kb], kf, sc[i][jb], 0, 0, 0);
            }
        }
        // ---- scale + mask (in place) ----
        const bool domask = (s0 + 63 > q0w);
#pragma unroll
        for (int i = 0; i < 2; ++i)
#pragma unroll
            for (int jb = 0; jb < 4; ++jb)
#pragma unroll
                for (int r = 0; r < 4; ++r) {
                    float v = sc[i][jb][r] * SCALE_;
                    if (domask) {
                        int qg = q0w + i * 16 + rbase + r;
                        int kg = s0 + jb * 16 + fro;
                        if (kg > qg) v = -1e30f;
                    }
                    sc[i][jb][r] = v;
                }
        // ---- online softmax ----
        float mx[2][4], fs[2][4], rs[2][4];
#pragma unroll
        for (int i = 0; i < 2; ++i)
#pragma unroll
            for (int r = 0; r < 4; ++r)
                mx[i][r] = fmaxf(fmaxf(sc[i][0][r], sc[i][1][r]), fmaxf(sc[i][2][r], sc[i][3][r]));
#pragma unroll
        for (int msk = 1; msk < 16; msk <<= 1)
#pragma unroll
            for (int i = 0; i < 2; ++i)
#pragma unroll
                for (int r = 0; r < 4; ++r) mx[i][r] = fmaxf(mx[i][r], __shfl_xor(mx[i][r], msk));
#pragma unroll
        for (int i = 0; i < 2; ++i)
#pragma unroll
            for (int r = 0; r < 4; ++r) {
                float mn = fmaxf(m_r[i][r], mx[i][r]);
                fs[i][r] = __expf(m_r[i][r] - mn);
                m_r[i][r] = mn;
            }
#pragma unroll
        for (int i = 0; i < 2; ++i)
#pragma unroll
            for (int jb = 0; jb < 4; ++jb)
#pragma unroll
                for (int r = 0; r < 4; ++r) sc[i][jb][r] = __expf(sc[i][jb][r] - m_r[i][r]);
#pragma unroll
        for (int i = 0; i < 2; ++i)
#pragma unroll
            for (int r = 0; r < 4; ++r)
                rs[i][r] = (sc[i][0][r] + sc[i][1][r]) + (sc[i][2][r] + sc[i][3][r]);
#pragma unroll
        for (int msk = 1; msk < 16; msk <<= 1)
#pragma unroll
            for (int i = 0; i < 2; ++i)
#pragma unroll
                for (int r = 0; r < 4; ++r) rs[i][r] += __shfl_xor(rs[i][r], msk);
#pragma unroll
        for (int i = 0; i < 2; ++i)
#pragma unroll
            for (int r = 0; r < 4; ++r) l_r[i][r] = l_r[i][r] * fs[i][r] + rs[i][r];
#pragma unroll
        for (int i = 0; i < 2; ++i)
#pragma unroll
            for (int d = 0; d < 8; ++d)
#pragma unroll
                for (int r = 0; r < 4; ++r) o[i][d][r] *= fs[i][r];
        // ---- P -> LDS (transpose to A-layout) ----
        unsigned short* pw = &Ps[wid][0];
#pragma unroll
        for (int i = 0; i < 2; ++i)
#pragma unroll
            for (int jb = 0; jb < 4; ++jb)
#pragma unroll
                for (int r = 0; r < 4; ++r)
                    pw[(i * 16 + rbase + r) * 72 + jb * 16 + fro] = f2bf(sc[i][jb][r]);
        asm volatile("s_waitcnt lgkmcnt(0)" ::: "memory");
        __builtin_amdgcn_sched_barrier(0);
        short8 pa[2][2];
#pragma unroll
        for (int i = 0; i < 2; ++i)
#pragma unroll
            for (int ks = 0; ks < 2; ++ks)
                pa[i][ks] = *(const short8*)&Ps[wid][(i * 16 + fro) * 72 + ks * 32 + fk * 8];
        // ---- PV ----
#pragma unroll
        for (int ks = 0; ks < 2; ++ks)
#pragma unroll
            for (int db = 0; db < 8; ++db) {
                const int d = db * 16 + fro;
                short8 vf = *(const short8*)&Vs[d * 64 + 8 * ((ks * 4 + fk) ^ (d & 7))];
#pragma unroll
                for (int i = 0; i < 2; ++i)
                    o[i][db] = __builtin_amdgcn_mfma_f32_16x16x32_bf16(pa[i][ks], vf, o[i][db], 0, 0, 0);
            }
    }
    // ---- epilogue: 1/l, sigmoid gate, store bf16 ----
#pragma unroll
    for (int i = 0; i < 2; ++i)
#pragma unroll
        for (int r = 0; r < 4; ++r) {
            const int qrow = q0w + i * 16 + rbase + r;
            float gv = bf2f(qkv[(size_t)(b * T_ + qrow) * NPAD + QKVD + h]);
            float sg = 1.f / (1.f + __expf(-gv));
            float invl = sg / l_r[i][r];
            unsigned short* orow = ao + (size_t)(b * T_ + qrow) * 2048 + h * 128;
#pragma unroll
            for (int db = 0; db < 8; ++db)
                orow[db * 16 + fro] = f2bf(o[i][db][r] * invl);
        }
}

extern "C" void kernel_launch(void* const* d_in, const int* in_sizes, int n_in,
                              void* d_out, int out_size, void* d_ws, size_t ws_size,
                              hipStream_t stream) {
    const float* x      = (const float*)d_in[0];
    const float* cosT   = (const float*)d_in[1];
    const float* sinT   = (const float*)d_in[2];
    const float* W_attn = (const float*)d_in[3];
    const float* qw     = (const float*)d_in[4];
    const float* kw     = (const float*)d_in[5];
    const float* W_proj = (const float*)d_in[6];

    char* ws = (char*)d_ws;
    const size_t OFF_XB   = 0;                       // 4096*2048*2   = 16777216
    const size_t OFF_WAB  = 16777216;                // 3200*2048*2   = 13107200
    const size_t OFF_WPB  = 29884416;                // 2048*2048*2   =  8388608
    const size_t OFF_QKV  = 38273024;                // 4096*3200*2   = 26214400
    const size_t OFF_VT   = 64487424;                // 2*4*128*2048*2=  4194304
    const size_t OFF_AO   = 68681728;                // 4096*2048*2   = 16777216
    const size_t NEED     = 85458944;
    if (ws_size < NEED) return;

    unsigned short* xb   = (unsigned short*)(ws + OFF_XB);
    unsigned short* wab  = (unsigned short*)(ws + OFF_WAB);
    unsigned short* wpb  = (unsigned short*)(ws + OFF_WPB);
    unsigned short* qkvb = (unsigned short*)(ws + OFF_QKV);
    unsigned short* vtb  = (unsigned short*)(ws + OFF_VT);
    unsigned short* aob  = (unsigned short*)(ws + OFF_AO);

    k_convert<<<8192, 256, 0, stream>>>(x,      xb,  2097152, 2097152);
    k_convert<<<6400, 256, 0, stream>>>(W_attn, wab, 1581056, 1638400);
    k_convert<<<4096, 256, 0, stream>>>(W_proj, wpb, 1048576, 1048576);
    k_gemm_nt<unsigned short><<<dim3(32, 25), 256, 0, stream>>>(xb, wab, qkvb, 2048, 2048, 2048, NPAD);
    k_normrope<<<20480, 256, 0, stream>>>(qkvb, cosT, sinT, qw, kw);
    k_transposeV<<<dim3(8, 32, 2), 256, 0, stream>>>(qkvb, vtb);
    k_attn<<<512, 256, 0, stream>>>(qkvb, vtb, aob);
    k_gemm_nt<float><<<dim3(32, 16), 256, 0, stream>>>(aob, wpb, (float*)d_out, 2048, 2048, 2048, 2048);
}

// Round 5
// 259.282 us; speedup vs baseline: 2.0048x; 1.3082x over previous
//
#include <hip/hip_runtime.h>

#define T_   2048
#define BB   2
#define CC   2048
#define HH   16
#define GG   4
#define HSS  128
#define QKVD 3072          // (H+2G)*HS
#define NQKV 3088          // + H gate cols
#define NPAD 3200          // padded to 25*128
#define SCALE_ 0.08838834764831845f   // 1/sqrt(128)

typedef __attribute__((ext_vector_type(8))) short  short8;
typedef __attribute__((ext_vector_type(4))) float  f32x4;
typedef __attribute__((ext_vector_type(4))) int    v4i;
typedef __attribute__((ext_vector_type(4))) float  v4f;
typedef __attribute__((ext_vector_type(4))) unsigned short u16x4;

typedef const void __attribute__((address_space(1)))* gas1_t;
typedef void __attribute__((address_space(3)))* as3_t;

__device__ __forceinline__ void gl_lds16(const void* g, void* l) {
    __builtin_amdgcn_global_load_lds((gas1_t)g, (as3_t)l, 16, 0, 0);
}

__device__ __forceinline__ unsigned short f2bf(float f) {
    unsigned u = __float_as_uint(f);
    u += 0x7fffu + ((u >> 16) & 1u);   // RNE
    return (unsigned short)(u >> 16);
}
__device__ __forceinline__ float bf2f(unsigned short h) {
    return __uint_as_float(((unsigned)h) << 16);
}

// ---------------- f32 -> bf16 convert (with optional zero-pad tail) ----------------
__global__ void k_convert(const float* __restrict__ src, unsigned short* __restrict__ dst,
                          int n_src4, int n_dst4) {
    int i = blockIdx.x * blockDim.x + threadIdx.x;
    if (i >= n_dst4) return;
    u16x4 o;
    if (i < n_src4) {
        v4f v = *(const v4f*)(src + (size_t)i * 4);
        o[0] = f2bf(v[0]); o[1] = f2bf(v[1]); o[2] = f2bf(v[2]); o[3] = f2bf(v[3]);
    } else {
        o[0] = 0; o[1] = 0; o[2] = 0; o[3] = 0;
    }
    *(u16x4*)(dst + (size_t)i * 4) = o;
}

// ---------------- NT GEMM: C[m][n] = sum_k A[m][k]*B[n][k], bf16 in ----------------
template <typename OutT>
__launch_bounds__(256, 2)
__global__ void k_gemm_nt(const unsigned short* __restrict__ A,
                          const unsigned short* __restrict__ Bm,
                          OutT* __restrict__ C,
                          int K, int lda, int ldb, int ldc) {
    __shared__ unsigned short As[128 * 64];
    __shared__ unsigned short Bs[128 * 64];
    const int t    = threadIdx.x;
    const int lane = t & 63;
    const int wid  = t >> 6;
    const int bm = blockIdx.x, bn = blockIdx.y;
    const int wm = (wid >> 1) * 64, wn = (wid & 1) * 64;

    f32x4 acc[4][4];
#pragma unroll
    for (int i = 0; i < 4; ++i)
#pragma unroll
        for (int j = 0; j < 4; ++j)
            acc[i][j] = (f32x4){0.f, 0.f, 0.f, 0.f};

    const int fro = lane & 15;
    const int fko = (lane >> 4) * 8;
    const int lrow = lane >> 3, lcol = (lane & 7) * 8;

    for (int kt = 0; kt < K; kt += 64) {
        __syncthreads();
#pragma unroll
        for (int p = 0; p < 4; ++p) {
            const int ra = wid * 32 + p * 8;
            gl_lds16(A  + (size_t)(bm * 128 + ra + lrow) * lda + kt + lcol, &As[ra * 64]);
            gl_lds16(Bm + (size_t)(bn * 128 + ra + lrow) * ldb + kt + lcol, &Bs[ra * 64]);
        }
        __syncthreads();
#pragma unroll
        for (int kk = 0; kk < 2; ++kk) {
            short8 af[4], bfr[4];
#pragma unroll
            for (int i = 0; i < 4; ++i)
                af[i] = *(const short8*)&As[(wm + i * 16 + fro) * 64 + kk * 32 + fko];
#pragma unroll
            for (int j = 0; j < 4; ++j)
                bfr[j] = *(const short8*)&Bs[(wn + j * 16 + fro) * 64 + kk * 32 + fko];
#pragma unroll
            for (int i = 0; i < 4; ++i)
#pragma unroll
                for (int j = 0; j < 4; ++j)
                    acc[i][j] = __builtin_amdgcn_mfma_f32_16x16x32_bf16(af[i], bfr[j], acc[i][j], 0, 0, 0);
        }
    }
    const int col = lane & 15, rbase = (lane >> 4) * 4;
#pragma unroll
    for (int i = 0; i < 4; ++i)
#pragma unroll
        for (int j = 0; j < 4; ++j)
#pragma unroll
            for (int r = 0; r < 4; ++r) {
                int grow = bm * 128 + wm + i * 16 + rbase + r;
                int gcol = bn * 128 + wn + j * 16 + col;
                float v = acc[i][j][r];
                if constexpr (sizeof(OutT) == 2)
                    C[(size_t)grow * ldc + gcol] = (OutT)f2bf(v);
                else
                    C[(size_t)grow * ldc + gcol] = (OutT)v;
            }
}

// ---------------- fused RMSNorm + RoPE, in place on q/k regions of qkv -------------
__global__ void k_normrope(unsigned short* __restrict__ qkv,
                           const float* __restrict__ cosT, const float* __restrict__ sinT,
                           const float* __restrict__ qw, const float* __restrict__ kw) {
    const int lane = threadIdx.x & 63;
    const int row  = blockIdx.x * 4 + (threadIdx.x >> 6);  // 0 .. 4096*20-1
    const int tok  = row / 20;
    const int hh   = row - tok * 20;
    const int tpos = tok & (T_ - 1);
    unsigned short* rp = qkv + (size_t)tok * NPAD + (hh < 16 ? hh * 128 : 2048 + (hh - 16) * 128);
    const float* w = (hh < 16) ? qw : kw;
    float e1 = bf2f(rp[lane]);
    float e2 = bf2f(rp[lane + 64]);
    float ss = e1 * e1 + e2 * e2;
#pragma unroll
    for (int m = 1; m < 64; m <<= 1) ss += __shfl_xor(ss, m);
    float inv = rsqrtf(ss * (1.0f / 128.0f) + 1e-5f);
    float n1 = e1 * inv * w[lane];
    float n2 = e2 * inv * w[lane + 64];
    float c = cosT[tpos * 64 + lane];
    float s = sinT[tpos * 64 + lane];
    rp[lane]      = f2bf(n1 * c - n2 * s);
    rp[lane + 64] = f2bf(n2 * c + n1 * s);
}

// ---------------- V transpose: VT[b][g][d][s] = V[b][s][g][d] ----------------------
__global__ void k_transposeV(const unsigned short* __restrict__ qkv,
                             unsigned short* __restrict__ vt) {
    __shared__ unsigned short tile[64][65];
    const int b = blockIdx.x >> 2, g = blockIdx.x & 3;
    const int s0 = blockIdx.y * 64, d0 = blockIdx.z * 64;
    const int tx = threadIdx.x & 63, ty0 = threadIdx.x >> 6;
    const unsigned short* src = qkv + (size_t)(b * T_ + s0) * NPAD + 2560 + g * 128 + d0;
#pragma unroll
    for (int r = 0; r < 16; ++r) {
        int ty = ty0 * 16 + r;
        tile[ty][tx] = src[(size_t)ty * NPAD + tx];
    }
    __syncthreads();
    unsigned short* dstp = vt + ((size_t)(b * GG + g) * 128 + d0) * T_ + s0;
#pragma unroll
    for (int r = 0; r < 16; ++r) {
        int ty = ty0 * 16 + r;
        dstp[(size_t)ty * T_ + tx] = tile[tx][ty];
    }
}

// ---------------- flash attention + gate ------------------------------------------
// 512 uniform blocks: block = (b,g,hh, pair p) handles q-tiles p and 31-p (64 rows
// each, 4 waves x 16 rows). K/V double-buffered in LDS via global_load_lds with
// inverse-XOR-swizzled source (rule 21); 1 barrier per KV tile (T3-minimum).
__launch_bounds__(256, 2)
__global__ void k_attn(const unsigned short* __restrict__ qkv,
                       const unsigned short* __restrict__ vt,
                       unsigned short* __restrict__ ao) {
    __shared__ unsigned short Ks[2][64 * 128];   // [buf][row kv][slot]  16KB each
    __shared__ unsigned short Vs[2][128 * 64];   // [buf][row d ][slot]  16KB each
    __shared__ unsigned short Ps[4][16 * 72];
    const int t = threadIdx.x;
    const int lane = t & 63;
    const int wid  = t >> 6;
    const int id = blockIdx.x;
    const int bg = id & 7;               // -> XCD (round-robin dispatch assumed)
    const int hh = (id >> 3) & 3;
    const int pr = id >> 5;              // 0..15
    const int b = bg >> 2, g = bg & 3, h = g * 4 + hh;
    const int fro = lane & 15, fk = lane >> 4;
    const int rbase = fk * 4;

    const unsigned short* kg0 = qkv + (size_t)(b * T_) * NPAD + 2048 + g * 128;
    const unsigned short* vg0 = vt + (size_t)(b * GG + g) * 128 * T_;

    // staging geometry: per wave 4 calls, each call = 1KB of LDS (64 lanes x 16B)
    const int cp0 = wid * 4;
    int cur = 0;

#pragma unroll
    for (int seg = 0; seg < 2; ++seg) {
        const int qt = (seg == 0) ? pr : 31 - pr;
        const int q0w = qt * 64 + wid * 16;

        // Q fragments: rows q0w+fro, k-chunks kb*32 + fk*8
        short8 qf[4];
        const unsigned short* qp = qkv + (size_t)(b * T_ + q0w + fro) * NPAD + h * 128 + fk * 8;
#pragma unroll
        for (int kb = 0; kb < 4; ++kb) qf[kb] = *(const short8*)(qp + kb * 32);

        float m_r[4], l_r[4];
        f32x4 o[8];
#pragma unroll
        for (int r = 0; r < 4; ++r) { m_r[r] = -1e30f; l_r[r] = 0.f; }
#pragma unroll
        for (int d = 0; d < 8; ++d) o[d] = (f32x4){0.f, 0.f, 0.f, 0.f};

        const int nt = qt + 1;

        // prologue: stage tile 0 into buf[cur]
#pragma unroll
        for (int p = 0; p < 4; ++p) {
            const int cp = cp0 + p;
            const int kr = cp * 4 + (lane >> 4);
            const int sK = lane & 15;
            gl_lds16(kg0 + (size_t)(0 + kr) * NPAD + (size_t)((sK ^ (kr & 7)) * 8), &Ks[cur][cp * 512]);
            const int d  = cp * 8 + (lane >> 3);
            const int sV = lane & 7;
            gl_lds16(vg0 + (size_t)d * T_ + 0 + (size_t)((sV ^ (d & 7)) * 8), &Vs[cur][cp * 512]);
        }
        __syncthreads();

        for (int ti = 0; ti < nt; ++ti) {
            // stage next tile into buf[cur^1] (overlaps with compute below)
            if (ti + 1 < nt) {
                const int sn = (ti + 1) * 64;
#pragma unroll
                for (int p = 0; p < 4; ++p) {
                    const int cp = cp0 + p;
                    const int kr = cp * 4 + (lane >> 4);
                    const int sK = lane & 15;
                    gl_lds16(kg0 + (size_t)(sn + kr) * NPAD + (size_t)((sK ^ (kr & 7)) * 8), &Ks[cur ^ 1][cp * 512]);
                    const int d  = cp * 8 + (lane >> 3);
                    const int sV = lane & 7;
                    gl_lds16(vg0 + (size_t)d * T_ + sn + (size_t)((sV ^ (d & 7)) * 8), &Vs[cur ^ 1][cp * 512]);
                }
            }
            // ---- QK^T on buf[cur]: S[16 q][64 kv] ----
            f32x4 sc[4];
#pragma unroll
            for (int jb = 0; jb < 4; ++jb) sc[jb] = (f32x4){0.f, 0.f, 0.f, 0.f};
#pragma unroll
            for (int jb = 0; jb < 4; ++jb) {
                const int kr = jb * 16 + fro;
#pragma unroll
                for (int kb = 0; kb < 4; ++kb) {
                    short8 kf = *(const short8*)&Ks[cur][kr * 128 + 8 * ((kb * 4 + fk) ^ (kr & 7))];
                    sc[jb] = __builtin_amdgcn_mfma_f32_16x16x32_bf16(qf[kb], kf, sc[jb], 0, 0, 0);
                }
            }
            // ---- scale + causal mask (diagonal tile only) ----
            const bool domask = (ti == qt);
#pragma unroll
            for (int jb = 0; jb < 4; ++jb)
#pragma unroll
                for (int r = 0; r < 4; ++r) {
                    float v = sc[jb][r] * SCALE_;
                    if (domask && (jb * 16 + fro) > (wid * 16 + rbase + r)) v = -1e30f;
                    sc[jb][r] = v;
                }
            // ---- online softmax (rows owned by 16-lane fro-groups) ----
            float mx[4], fs[4], rs[4];
#pragma unroll
            for (int r = 0; r < 4; ++r)
                mx[r] = fmaxf(fmaxf(sc[0][r], sc[1][r]), fmaxf(sc[2][r], sc[3][r]));
#pragma unroll
            for (int msk = 1; msk < 16; msk <<= 1)
#pragma unroll
                for (int r = 0; r < 4; ++r) mx[r] = fmaxf(mx[r], __shfl_xor(mx[r], msk));
#pragma unroll
            for (int r = 0; r < 4; ++r) {
                float mn = fmaxf(m_r[r], mx[r]);
                fs[r] = __expf(m_r[r] - mn);
                m_r[r] = mn;
            }
#pragma unroll
            for (int jb = 0; jb < 4; ++jb)
#pragma unroll
                for (int r = 0; r < 4; ++r) sc[jb][r] = __expf(sc[jb][r] - m_r[r]);
#pragma unroll
            for (int r = 0; r < 4; ++r)
                rs[r] = (sc[0][r] + sc[1][r]) + (sc[2][r] + sc[3][r]);
#pragma unroll
            for (int msk = 1; msk < 16; msk <<= 1)
#pragma unroll
                for (int r = 0; r < 4; ++r) rs[r] += __shfl_xor(rs[r], msk);
#pragma unroll
            for (int r = 0; r < 4; ++r) l_r[r] = l_r[r] * fs[r] + rs[r];
#pragma unroll
            for (int d = 0; d < 8; ++d)
#pragma unroll
                for (int r = 0; r < 4; ++r) o[d][r] *= fs[r];
            // ---- P -> LDS (per-wave transpose to A-layout) ----
            unsigned short* pw = &Ps[wid][0];
#pragma unroll
            for (int jb = 0; jb < 4; ++jb)
#pragma unroll
                for (int r = 0; r < 4; ++r)
                    pw[(rbase + r) * 72 + jb * 16 + fro] = f2bf(sc[jb][r]);
            asm volatile("s_waitcnt lgkmcnt(0)" ::: "memory");
            __builtin_amdgcn_sched_barrier(0);
            short8 pa[2];
#pragma unroll
            for (int ks = 0; ks < 2; ++ks)
                pa[ks] = *(const short8*)&Ps[wid][fro * 72 + ks * 32 + fk * 8];
            // ---- PV on buf[cur] ----
#pragma unroll
            for (int ks = 0; ks < 2; ++ks)
#pragma unroll
                for (int db = 0; db < 8; ++db) {
                    const int d = db * 16 + fro;
                    short8 vf = *(const short8*)&Vs[cur][d * 64 + 8 * ((ks * 4 + fk) ^ (d & 7))];
                    o[db] = __builtin_amdgcn_mfma_f32_16x16x32_bf16(pa[ks], vf, o[db], 0, 0, 0);
                }
            // barrier: drains next-tile global_load_lds (overlapped with compute above)
            // and protects buf[cur^1] reuse.
            __syncthreads();
            cur ^= 1;
        }
        // ---- epilogue: 1/l, sigmoid gate, store bf16 ----
#pragma unroll
        for (int r = 0; r < 4; ++r) {
            const int qrow = q0w + rbase + r;
            float gv = bf2f(qkv[(size_t)(b * T_ + qrow) * NPAD + QKVD + h]);
            float sg = 1.f / (1.f + __expf(-gv));
            float invl = sg / l_r[r];
            unsigned short* orow = ao + (size_t)(b * T_ + qrow) * 2048 + h * 128;
#pragma unroll
            for (int db = 0; db < 8; ++db)
                orow[db * 16 + fro] = f2bf(o[db][r] * invl);
        }
    }
}

extern "C" void kernel_launch(void* const* d_in, const int* in_sizes, int n_in,
                              void* d_out, int out_size, void* d_ws, size_t ws_size,
                              hipStream_t stream) {
    const float* x      = (const float*)d_in[0];
    const float* cosT   = (const float*)d_in[1];
    const float* sinT   = (const float*)d_in[2];
    const float* W_attn = (const float*)d_in[3];
    const float* qw     = (const float*)d_in[4];
    const float* kw     = (const float*)d_in[5];
    const float* W_proj = (const float*)d_in[6];

    char* ws = (char*)d_ws;
    const size_t OFF_XB   = 0;                       // 4096*2048*2   = 16777216
    const size_t OFF_WAB  = 16777216;                // 3200*2048*2   = 13107200
    const size_t OFF_WPB  = 29884416;                // 2048*2048*2   =  8388608
    const size_t OFF_QKV  = 38273024;                // 4096*3200*2   = 26214400
    const size_t OFF_VT   = 64487424;                // 2*4*128*2048*2=  4194304
    const size_t OFF_AO   = 68681728;                // 4096*2048*2   = 16777216
    const size_t NEED     = 85458944;
    if (ws_size < NEED) return;

    unsigned short* xb   = (unsigned short*)(ws + OFF_XB);
    unsigned short* wab  = (unsigned short*)(ws + OFF_WAB);
    unsigned short* wpb  = (unsigned short*)(ws + OFF_WPB);
    unsigned short* qkvb = (unsigned short*)(ws + OFF_QKV);
    unsigned short* vtb  = (unsigned short*)(ws + OFF_VT);
    unsigned short* aob  = (unsigned short*)(ws + OFF_AO);

    k_convert<<<8192, 256, 0, stream>>>(x,      xb,  2097152, 2097152);
    k_convert<<<6400, 256, 0, stream>>>(W_attn, wab, 1581056, 1638400);
    k_convert<<<4096, 256, 0, stream>>>(W_proj, wpb, 1048576, 1048576);
    k_gemm_nt<unsigned short><<<dim3(32, 25), 256, 0, stream>>>(xb, wab, qkvb, 2048, 2048, 2048, NPAD);
    k_normrope<<<20480, 256, 0, stream>>>(qkvb, cosT, sinT, qw, kw);
    k_transposeV<<<dim3(8, 32, 2), 256, 0, stream>>>(qkvb, vtb);
    k_attn<<<512, 256, 0, stream>>>(qkvb, vtb, aob);
    k_gemm_nt<float><<<dim3(32, 16), 256, 0, stream>>>(aob, wpb, (float*)d_out, 2048, 2048, 2048, 2048);
}